// Round 1
// 879.275 us; speedup vs baseline: 1.0446x; 1.0446x over previous
//
#include <hip/hip_runtime.h>

// GRU: B=256, T=2048, I=2, H=128. One workgroup (4 waves) per batch element.
// R17: replace dot2+DPP-butterfly matvec with MFMA 16x16x32 f16 (B-broadcast).
// Rationale: kernel is LATENCY-bound (VALUBusy 29%, MfmaUtil 0, HBM 0.04%);
// step = ~1076 cyc serial chain; the matrix pipe is idle. Critical-path cycles
// are what count, not MFMA utilization (prev "MFMA GEMV falsified at 1/16
// utilization" was a throughput argument -- invalid in this regime).
// Mapping:
//  - wave w owns units [32w,32w+32): rows {128g + 32w + [0,32)}, g=r,z,n ->
//    6 row-tiles of 16; all three gates of a unit stay wave-local -> still
//    exactly ONE barrier per step (only h itself is exchanged, 256 B).
//  - A-frags (static, prescaled f16): lane l holds A[row=l&15][k=8*(l>>4)+e];
//    6 tiles x 4 K-chunks x 4 VGPR = 96 VGPRs, loaded once.
//  - B-frag per step: all 16 columns = h => lane l reads h[32c+8*(l>>4)..+8]
//    = 1 ds_read_b128 per K-chunk (4/lane, same 16 wave-reads as before,
//    broadcast within 16-lane groups, conflict-free). Every lane's D regs
//    then hold 4 complete row sums (x16 column-replicated): NO cross-lane
//    reduce, no DPP butterfly, no s_nop hazards.
//  - De-replication: m=l&15 (mod 8) picks (j'=m&1, reg=m>>1); lane runs the
//    full gate chain for ONE unit u = 32w + 16j' + 4*(l>>4) + reg; m<8 writes
//    fp16 h[u] into the double-buffered LDS h. 2-way b16 write conflict = free.
//  - xp/bias folded per-unit POST-MFMA (6 fma, computed during MFMA phase).
// Predicted step: drain ~190 || 24 chained MFMA ~120+lat -> ~250, + select
// tree ~50 + gate tail ~80 + write/barrier ~140  =>  ~650 us (from 918).
// Kept from R13: x staged in LDS w/ t+1 prefetch; exp2/rcp gates; prescaled
// fp16 weights; fp32 h recurrence in producer registers; one barrier/step.

#define BB 256
#define TT 2048
#define HH 128
#define NT 256

typedef _Float16 v8h __attribute__((ext_vector_type(8)));
typedef float    v4f __attribute__((ext_vector_type(4)));

__global__ __launch_bounds__(NT, 1) void gru_seq_kernel(
    const float* __restrict__ x,        // [B, T, 2]
    const int*   __restrict__ lengths,  // [B]
    const float* __restrict__ W_ih,     // [384, 2]
    const float* __restrict__ W_hh,     // [384, 128]
    const float* __restrict__ b_ih,     // [384]
    const float* __restrict__ b_hh,     // [384]
    const float* __restrict__ head_w,   // [128]
    const float* __restrict__ head_b,   // [1]
    float* __restrict__ out)            // [B]
{
    __shared__ __align__(16) float x_lds[(TT + 1) * 2];      // 16 KB (+prefetch pad)
    __shared__ __align__(16) _Float16 h_lds[2][HH];          // 2 x 256 B, dbuf
    __shared__ float red[HH];

    const int tid = threadIdx.x;
    const int w   = tid >> 6;        // wave 0..3
    const int l   = tid & 63;
    const int lg  = l >> 4;          // lane group 0..3 (k-chunk slice / D-row group)
    const int m   = l & 15;          // A row within tile; replica id for output
    const int m7  = m & 7;
    const int jsel = m7 & 1;         // which 16-row half-tile
    const int rsel = m7 >> 1;        // which D reg 0..3
    const int b  = blockIdx.x;
    const int len = lengths[b];

    const float S_RZ = -1.4426950408889634f;   // -log2(e)
    const float S_N  =  2.8853900817779268f;   //  2*log2(e)

    // --- A-frags: afrag[g*2+j'][c] = prescaled f16 of
    //     W_hh[128g + 32w + 16j' + m][32c + 8lg .. +8]
    v8h afrag[6][4];
    #pragma unroll
    for (int g = 0; g < 3; ++g) {
        const float s = (g == 2) ? S_N : S_RZ;
        #pragma unroll
        for (int jp = 0; jp < 2; ++jp) {
            const float* Wr = W_hh + (size_t)(128 * g + 32 * w + 16 * jp + m) * HH + 8 * lg;
            #pragma unroll
            for (int c = 0; c < 4; ++c) {
                const float4 w0 = *(const float4*)(Wr + 32 * c);
                const float4 w1 = *(const float4*)(Wr + 32 * c + 4);
                afrag[g * 2 + jp][c] = (v8h){
                    (_Float16)(s * w0.x), (_Float16)(s * w0.y),
                    (_Float16)(s * w0.z), (_Float16)(s * w0.w),
                    (_Float16)(s * w1.x), (_Float16)(s * w1.y),
                    (_Float16)(s * w1.z), (_Float16)(s * w1.w)};
            }
        }
    }

    // --- this lane's unit and per-unit scalars (xp/bias terms, prescaled) ---
    const int u = 32 * w + 16 * jsel + 4 * lg + rsel;
    const float cr0 = S_RZ * W_ih[u * 2];
    const float cr1 = S_RZ * W_ih[u * 2 + 1];
    const float crb = S_RZ * (b_ih[u] + b_hh[u]);
    const float cz0 = S_RZ * W_ih[(HH + u) * 2];
    const float cz1 = S_RZ * W_ih[(HH + u) * 2 + 1];
    const float czb = S_RZ * (b_ih[HH + u] + b_hh[HH + u]);
    const float cn0 = S_N * W_ih[(2 * HH + u) * 2];
    const float cn1 = S_N * W_ih[(2 * HH + u) * 2 + 1];
    const float cnbi = S_N * b_ih[2 * HH + u];
    const float cnbh = S_N * b_hh[2 * HH + u];
    const float hw   = head_w[u];

    // --- stage x[b] into LDS (float4, coalesced) ---
    {
        const float4* xb4 = (const float4*)(x + (size_t)b * TT * 2);
        float4* xl4 = (float4*)x_lds;
        #pragma unroll
        for (int i = tid; i < TT * 2 / 4; i += NT) xl4[i] = xb4[i];
    }
    if (tid == 0) { x_lds[TT * 2] = 0.f; x_lds[TT * 2 + 1] = 0.f; }
    for (int i = tid; i < 2 * HH; i += NT) ((_Float16*)h_lds)[i] = (_Float16)0.f;

    __syncthreads();

    float h_reg = 0.0f;              // fp32 h[u]; maintained in all replicas
    int buf = 0;
    const float2* x2 = (const float2*)x_lds;
    float2 xt = x2[0];
    const v4f zero = {0.f, 0.f, 0.f, 0.f};

    for (int t = 0; t < len; ++t) {
        // h B-frags: 4 x ds_read_b128 (16-lane broadcast per address, conflict-free)
        const v8h* hb = (const v8h*)(h_lds[buf]);
        const v8h B0 = hb[lg];
        const v8h B1 = hb[4 + lg];
        const v8h B2 = hb[8 + lg];
        const v8h B3 = hb[12 + lg];

        const float2 xt_next = x2[t + 1];   // prefetch (pad-safe at t = len-1)

        // xp terms: independent of h, hide under MFMA phase
        const float xpr = fmaf(cr0, xt.x, fmaf(cr1, xt.y, crb));
        const float xpz = fmaf(cz0, xt.x, fmaf(cz1, xt.y, czb));
        const float xpn = fmaf(cn0, xt.x, fmaf(cn1, xt.y, cnbi));

        // 24 MFMAs: 6 independent tiles x 4 chained K-chunks
        v4f acc[6];
        #pragma unroll
        for (int j = 0; j < 6; ++j)
            acc[j] = __builtin_amdgcn_mfma_f32_16x16x32_f16(afrag[j][0], B0, zero, 0, 0, 0);
        #pragma unroll
        for (int j = 0; j < 6; ++j)
            acc[j] = __builtin_amdgcn_mfma_f32_16x16x32_f16(afrag[j][1], B1, acc[j], 0, 0, 0);
        #pragma unroll
        for (int j = 0; j < 6; ++j)
            acc[j] = __builtin_amdgcn_mfma_f32_16x16x32_f16(afrag[j][2], B2, acc[j], 0, 0, 0);
        #pragma unroll
        for (int j = 0; j < 6; ++j)
            acc[j] = __builtin_amdgcn_mfma_f32_16x16x32_f16(afrag[j][3], B3, acc[j], 0, 0, 0);

        // de-replication: pick this lane's (j', reg) -- 7 cndmask per gate
        float arS, azS, anS;
        #define PICK(g, dst) do {                                              \
            const float _l0 = (rsel & 1) ? acc[2*(g)][1]     : acc[2*(g)][0];  \
            const float _h0 = (rsel & 1) ? acc[2*(g)][3]     : acc[2*(g)][2];  \
            const float _v0 = (rsel & 2) ? _h0 : _l0;                          \
            const float _l1 = (rsel & 1) ? acc[2*(g)+1][1]   : acc[2*(g)+1][0];\
            const float _h1 = (rsel & 1) ? acc[2*(g)+1][3]   : acc[2*(g)+1][2];\
            const float _v1 = (rsel & 2) ? _h1 : _l1;                          \
            (dst) = jsel ? _v1 : _v0;                                          \
        } while (0)
        PICK(0, arS); PICK(1, azS); PICK(2, anS);
        #undef PICK

        // gate chain (prescaled: sigmoid(v) = rcp(1+exp2(S_RZ*v)),
        //             tanh(y) = 1 - 2*rcp(1+exp2(S_N*y)))
        const float ar = arS + xpr;
        const float az = azS + xpz;
        const float r  = __builtin_amdgcn_rcpf(1.f + __builtin_amdgcn_exp2f(ar));
        const float z  = __builtin_amdgcn_rcpf(1.f + __builtin_amdgcn_exp2f(az));
        const float an = anS + cnbh;
        const float uu = __builtin_amdgcn_exp2f(fmaf(r, an, xpn));
        const float n  = fmaf(-2.f, __builtin_amdgcn_rcpf(1.f + uu), 1.f);
        const float h_new = n + z * (h_reg - n);
        h_reg = h_new;
        if (m < 8) h_lds[buf ^ 1][u] = (_Float16)h_new;
        __syncthreads();
        buf ^= 1;
        xt = xt_next;
    }

    // --- head: out[b] = dot(h, head_w) + head_b ---
    if (m < 8) red[u] = h_reg * hw;
    __syncthreads();
    if (tid < 64) {
        float v = red[tid] + red[tid + 64];
        #pragma unroll
        for (int off = 32; off > 0; off >>= 1) v += __shfl_xor(v, off, 64);
        if (tid == 0) out[b] = v + head_b[0];
    }
}

extern "C" void kernel_launch(void* const* d_in, const int* in_sizes, int n_in,
                              void* d_out, int out_size, void* d_ws, size_t ws_size,
                              hipStream_t stream) {
    const float* x      = (const float*)d_in[0];
    const int*   len    = (const int*)  d_in[1];
    const float* W_ih   = (const float*)d_in[2];
    const float* W_hh   = (const float*)d_in[3];
    const float* b_ih   = (const float*)d_in[4];
    const float* b_hh   = (const float*)d_in[5];
    const float* head_w = (const float*)d_in[6];
    const float* head_b = (const float*)d_in[7];
    float* out = (float*)d_out;

    gru_seq_kernel<<<BB, NT, 0, stream>>>(x, len, W_ih, W_hh, b_ih, b_hh,
                                          head_w, head_b, out);
}

// Round 2
// 860.729 us; speedup vs baseline: 1.0671x; 1.0215x over previous
//
#include <hip/hip_runtime.h>

// GRU: B=256, T=2048, I=2, H=128. One workgroup per batch element.
// R18: 8 waves (NT=512, 2/SIMD), 3 row-tiles per wave (one per gate).
// Rationale: R17 step ~815 cyc @~1.9GHz = 165 VALU + 155 MFMA + ~495 idle
// (chain latency, unhidden at 1 wave/SIMD). All serial terms scale with
// per-wave chain length: halve MFMA phase (24->12 ops), split K-chains
// 4-deep -> 2x2-deep (+v4f add), select tree 21 -> 9 cndmask (jsel gone:
// tile == gate), and 2 waves/SIMD interleave to fill dep-stall slots.
// LDS h-reads are 16-lane same-address broadcasts (conflict-free, m136);
// traffic doubles but should dedupe -- main downside risk (flat if not).
// Mapping (wave w owns units [16w,16w+16)):
//  - A-frags: afrag[g][kc] = prescaled f16 W_hh[128g+16w+(l&15)][32kc+8lg+e],
//    3 tiles x 4 K-chunks x 4 VGPR = 48 VGPRs, loaded once.
//  - B-frags: all 16 cols = h; lane reads h[32c+8lg..+8], 4x ds_read_b128.
//  - D: col=l&15 (replica), row=4lg+reg; lane consumes u=16w+4lg+(col&3)
//    via 3-cndmask reg-select per gate; replica col>>2==0 produces h[u].
// Kept from R17: prescaled fp16 weights, exp2/rcp gates, xp folded post-
// select, x in LDS with t+1 prefetch, fp32 h recurrence, 1 barrier/step.

#define BB 256
#define TT 2048
#define HH 128
#define NT 512

typedef _Float16 v8h __attribute__((ext_vector_type(8)));
typedef float    v4f __attribute__((ext_vector_type(4)));

__global__ __launch_bounds__(NT, 1) void gru_seq_kernel(
    const float* __restrict__ x,        // [B, T, 2]
    const int*   __restrict__ lengths,  // [B]
    const float* __restrict__ W_ih,     // [384, 2]
    const float* __restrict__ W_hh,     // [384, 128]
    const float* __restrict__ b_ih,     // [384]
    const float* __restrict__ b_hh,     // [384]
    const float* __restrict__ head_w,   // [128]
    const float* __restrict__ head_b,   // [1]
    float* __restrict__ out)            // [B]
{
    __shared__ __align__(16) float x_lds[(TT + 1) * 2];      // 16 KB (+prefetch pad)
    __shared__ __align__(16) _Float16 h_lds[2][HH];          // 2 x 256 B, dbuf
    __shared__ float red[HH];

    const int tid = threadIdx.x;
    const int w    = tid >> 6;       // wave 0..7: owns units [16w, 16w+16)
    const int l    = tid & 63;
    const int lg   = l >> 4;         // k-slice / D-row group
    const int m    = l & 15;         // A row within tile = D col (replica id)
    const int rsel = m & 3;          // which D reg this lane consumes
    const int rep  = m >> 2;         // replica 0..3; rep==0 produces
    const int b  = blockIdx.x;
    const int len = lengths[b];

    const float S_RZ = -1.4426950408889634f;   // -log2(e)
    const float S_N  =  2.8853900817779268f;   //  2*log2(e)

    // --- A-frags: afrag[g][kc] = prescaled f16 of
    //     W_hh[128g + 16w + m][32kc + 8lg .. +8]
    v8h afrag[3][4];
    #pragma unroll
    for (int g = 0; g < 3; ++g) {
        const float s = (g == 2) ? S_N : S_RZ;
        const float* Wr = W_hh + (size_t)(128 * g + 16 * w + m) * HH + 8 * lg;
        #pragma unroll
        for (int kc = 0; kc < 4; ++kc) {
            const float4 w0 = *(const float4*)(Wr + 32 * kc);
            const float4 w1 = *(const float4*)(Wr + 32 * kc + 4);
            afrag[g][kc] = (v8h){
                (_Float16)(s * w0.x), (_Float16)(s * w0.y),
                (_Float16)(s * w0.z), (_Float16)(s * w0.w),
                (_Float16)(s * w1.x), (_Float16)(s * w1.y),
                (_Float16)(s * w1.z), (_Float16)(s * w1.w)};
        }
    }

    // --- this lane's unit and per-unit scalars (xp/bias terms, prescaled) ---
    const int u = 16 * w + 4 * lg + rsel;
    const float cr0 = S_RZ * W_ih[u * 2];
    const float cr1 = S_RZ * W_ih[u * 2 + 1];
    const float crb = S_RZ * (b_ih[u] + b_hh[u]);
    const float cz0 = S_RZ * W_ih[(HH + u) * 2];
    const float cz1 = S_RZ * W_ih[(HH + u) * 2 + 1];
    const float czb = S_RZ * (b_ih[HH + u] + b_hh[HH + u]);
    const float cn0 = S_N * W_ih[(2 * HH + u) * 2];
    const float cn1 = S_N * W_ih[(2 * HH + u) * 2 + 1];
    const float cnbi = S_N * b_ih[2 * HH + u];
    const float cnbh = S_N * b_hh[2 * HH + u];
    const float hw   = head_w[u];

    // --- stage x[b] into LDS (float4, coalesced) ---
    {
        const float4* xb4 = (const float4*)(x + (size_t)b * TT * 2);
        float4* xl4 = (float4*)x_lds;
        #pragma unroll
        for (int i = tid; i < TT * 2 / 4; i += NT) xl4[i] = xb4[i];
    }
    if (tid == 0) { x_lds[TT * 2] = 0.f; x_lds[TT * 2 + 1] = 0.f; }
    for (int i = tid; i < 2 * HH; i += NT) ((_Float16*)h_lds)[i] = (_Float16)0.f;

    __syncthreads();

    float h_reg = 0.0f;              // fp32 h[u]; maintained in all replicas
    int buf = 0;
    const float2* x2 = (const float2*)x_lds;
    float2 xt = x2[0];
    const v4f zero = {0.f, 0.f, 0.f, 0.f};

    for (int t = 0; t < len; ++t) {
        // h B-frags: 4 x ds_read_b128 (16-lane same-address broadcast)
        const v8h* hb = (const v8h*)(h_lds[buf]);
        const v8h B0 = hb[lg];
        const v8h B1 = hb[4 + lg];
        const v8h B2 = hb[8 + lg];
        const v8h B3 = hb[12 + lg];

        const float2 xt_next = x2[t + 1];   // prefetch (pad-safe at t = len-1)

        // xp terms: independent of h, hide under MFMA phase
        const float xpr = fmaf(cr0, xt.x, fmaf(cr1, xt.y, crb));
        const float xpz = fmaf(cz0, xt.x, fmaf(cz1, xt.y, czb));
        const float xpn = fmaf(cn0, xt.x, fmaf(cn1, xt.y, cnbi));

        // 12 MFMAs: 3 tiles x (2 + 2 chained K-chunks), two accs per tile
        v4f accA[3], accB[3];
        #pragma unroll
        for (int g = 0; g < 3; ++g)
            accA[g] = __builtin_amdgcn_mfma_f32_16x16x32_f16(afrag[g][0], B0, zero, 0, 0, 0);
        #pragma unroll
        for (int g = 0; g < 3; ++g)
            accB[g] = __builtin_amdgcn_mfma_f32_16x16x32_f16(afrag[g][2], B2, zero, 0, 0, 0);
        #pragma unroll
        for (int g = 0; g < 3; ++g)
            accA[g] = __builtin_amdgcn_mfma_f32_16x16x32_f16(afrag[g][1], B1, accA[g], 0, 0, 0);
        #pragma unroll
        for (int g = 0; g < 3; ++g)
            accB[g] = __builtin_amdgcn_mfma_f32_16x16x32_f16(afrag[g][3], B3, accB[g], 0, 0, 0);

        // de-replication: 3 cndmask per gate (reg-select only; tile == gate)
        float arS, azS, anS;
        #define PICK(g, dst) do {                                        \
            const v4f _s = accA[g] + accB[g];                            \
            const float _v01 = (rsel & 1) ? _s[1] : _s[0];               \
            const float _v23 = (rsel & 1) ? _s[3] : _s[2];               \
            (dst) = (rsel & 2) ? _v23 : _v01;                            \
        } while (0)
        PICK(0, arS); PICK(1, azS); PICK(2, anS);
        #undef PICK

        // gate chain (prescaled: sigmoid(v) = rcp(1+exp2(S_RZ*v)),
        //             tanh(y) = 1 - 2*rcp(1+exp2(S_N*y)))
        const float ar = arS + xpr;
        const float az = azS + xpz;
        const float r  = __builtin_amdgcn_rcpf(1.f + __builtin_amdgcn_exp2f(ar));
        const float z  = __builtin_amdgcn_rcpf(1.f + __builtin_amdgcn_exp2f(az));
        const float an = anS + cnbh;
        const float uu = __builtin_amdgcn_exp2f(fmaf(r, an, xpn));
        const float n  = fmaf(-2.f, __builtin_amdgcn_rcpf(1.f + uu), 1.f);
        const float h_new = n + z * (h_reg - n);
        h_reg = h_new;
        if (rep == 0) h_lds[buf ^ 1][u] = (_Float16)h_new;
        __syncthreads();
        buf ^= 1;
        xt = xt_next;
    }

    // --- head: out[b] = dot(h, head_w) + head_b ---
    if (rep == 0) red[u] = h_reg * hw;
    __syncthreads();
    if (tid < 64) {
        float v = red[tid] + red[tid + 64];
        #pragma unroll
        for (int off = 32; off > 0; off >>= 1) v += __shfl_xor(v, off, 64);
        if (tid == 0) out[b] = v + head_b[0];
    }
}

extern "C" void kernel_launch(void* const* d_in, const int* in_sizes, int n_in,
                              void* d_out, int out_size, void* d_ws, size_t ws_size,
                              hipStream_t stream) {
    const float* x      = (const float*)d_in[0];
    const int*   len    = (const int*)  d_in[1];
    const float* W_ih   = (const float*)d_in[2];
    const float* W_hh   = (const float*)d_in[3];
    const float* b_ih   = (const float*)d_in[4];
    const float* b_hh   = (const float*)d_in[5];
    const float* head_w = (const float*)d_in[6];
    const float* head_b = (const float*)d_in[7];
    float* out = (float*)d_out;

    gru_seq_kernel<<<BB, NT, 0, stream>>>(x, len, W_ih, W_hh, b_ih, b_hh,
                                          head_w, head_b, out);
}